// Round 7
// baseline (522.660 us; speedup 1.0000x reference)
//
#include <hip/hip_runtime.h>
#include <hip/hip_bf16.h>
#include <math.h>

// Problem constants (from reference)
constexpr int kB  = 16;
constexpr int kN  = 512;
constexpr int kD  = 256;
constexpr int kH  = 8;
constexpr int kDK = 32;
constexpr int kL  = 4;

using bf16 = __hip_bfloat16;
using short8 = __attribute__((ext_vector_type(8))) short;   // 8 bf16 = 4 VGPR
using floatx4 = __attribute__((ext_vector_type(4))) float;  // MFMA C/D frag

// ---------------- block reduction helpers (256 threads = 4 waves) ----------
__device__ __forceinline__ float blockReduceSum(float v, float* sh) {
    #pragma unroll
    for (int o = 32; o > 0; o >>= 1) v += __shfl_down(v, o, 64);
    int lane = threadIdx.x & 63, w = threadIdx.x >> 6;
    __syncthreads();
    if (lane == 0) sh[w] = v;
    __syncthreads();
    return sh[0] + sh[1] + sh[2] + sh[3];
}

__device__ __forceinline__ float blockReduceMax(float v, float* sh) {
    #pragma unroll
    for (int o = 32; o > 0; o >>= 1) v = fmaxf(v, __shfl_down(v, o, 64));
    int lane = threadIdx.x & 63, w = threadIdx.x >> 6;
    __syncthreads();
    if (lane == 0) sh[w] = v;
    __syncthreads();
    return fmaxf(fmaxf(sh[0], sh[1]), fmaxf(sh[2], sh[3]));
}

// ---------------- weight transpose+convert: W[k][n] fp32 -> Wt[n][k] bf16 ---
__global__ __launch_bounds__(256) void wconv_kernel(const float* __restrict__ Wq,
                                                    const float* __restrict__ Wk,
                                                    const float* __restrict__ Wv,
                                                    const float* __restrict__ Wo,
                                                    const float* __restrict__ Wf1,
                                                    const float* __restrict__ Wf2,
                                                    bf16* __restrict__ wqkv,
                                                    bf16* __restrict__ wo,
                                                    bf16* __restrict__ wf1,
                                                    bf16* __restrict__ wf2) {
    __shared__ float tile[32][33];
    int bid = blockIdx.x;            // 24 * 64
    int mat = bid >> 6;
    int t6 = bid & 63;
    int tr = t6 >> 3, tc = t6 & 7;
    int layer = mat / 6, slot = mat % 6;
    const float* src =
        slot == 0 ? Wq : slot == 1 ? Wk : slot == 2 ? Wv :
        slot == 3 ? Wo : slot == 4 ? Wf1 : Wf2;
    src += (size_t)layer * kD * kD;
    bf16* dst;
    if (slot < 3) dst = wqkv + ((size_t)layer * 768 + slot * 256) * kD;
    else dst = (slot == 3 ? wo : slot == 4 ? wf1 : wf2) + (size_t)layer * kD * kD;
    int t = threadIdx.x;
    int r = t >> 5, c = t & 31;
    #pragma unroll
    for (int i = 0; i < 4; i++)
        tile[r + i * 8][c] = src[(size_t)(tr * 32 + r + i * 8) * kD + tc * 32 + c];
    __syncthreads();
    #pragma unroll
    for (int i = 0; i < 4; i++)
        dst[(size_t)(tc * 32 + r + i * 8) * kD + tr * 32 + c] = bf16(tile[c][r + i * 8]);
}

// ---------------- bias concat for QKV ---------------------------------------
__global__ __launch_bounds__(256) void bcat_kernel(const float* __restrict__ bq,
                                                   const float* __restrict__ bk,
                                                   const float* __restrict__ bv,
                                                   float* __restrict__ bcat) {
    int idx = blockIdx.x * 256 + threadIdx.x;
    int layer = idx / 768, j = idx % 768;
    const float* s = j < 256 ? bq : j < 512 ? bk : bv;
    bcat[idx] = s[layer * 256 + (j & 255)];
}

// ---------------- packed column mask: mpack[b][li] bit tt = mask[b][tt*16+li]
__global__ __launch_bounds__(256) void mpack_kernel(const int* __restrict__ mask,
                                                    unsigned* __restrict__ mp) {
    int t = threadIdx.x;            // 1 block of 256: b = t>>4, li = t&15
    int b = t >> 4, li = t & 15;
    unsigned bits = 0;
    #pragma unroll
    for (int tt = 0; tt < 32; tt++)
        bits |= (unsigned)(mask[b * kN + tt * 16 + li] != 0) << tt;
    mp[t] = bits;
}

// ---------------- pc = 0.3*softmax(mask? -dist : -inf) + 0.4*adj/rowsum ----
__global__ __launch_bounds__(256) void pc_kernel(const float* __restrict__ adj,
                                                 const float* __restrict__ dist,
                                                 const int* __restrict__ mask,
                                                 bf16* __restrict__ pcb) {
    __shared__ float sh[4];
    int row = blockIdx.x;
    int b = row >> 9;
    int t = threadIdx.x;
    const float* dr = dist + (size_t)row * kN;
    const float* ar = adj + (size_t)row * kN;
    const int* mr = mask + b * kN;
    float d0 = dr[t], d1 = dr[t + 256];
    float a0 = ar[t], a1 = ar[t + 256];
    int m0 = mr[t], m1 = mr[t + 256];
    float s0 = m0 ? -d0 : -INFINITY;
    float s1 = m1 ? -d1 : -INFINITY;
    float mx = blockReduceMax(fmaxf(s0, s1), sh);
    float e0 = __expf(s0 - mx);
    float e1 = __expf(s1 - mx);
    float sum  = blockReduceSum(e0 + e1, sh);
    float asum = blockReduceSum(a0 + a1, sh);
    float w_d = 0.3f / sum;
    float w_a = 0.4f / (asum + 1e-6f);
    bf16* pr = pcb + (size_t)row * kN;
    pr[t]       = bf16(e0 * w_d + a0 * w_a);
    pr[t + 256] = bf16(e1 * w_d + a1 * w_a);
}

// ---------------- LayerNorm (ddof=1, eps added to std) ---------------------
template <typename OT>
__global__ __launch_bounds__(256) void ln_kernel(const float* __restrict__ x,
                                                 const float* __restrict__ ga,
                                                 const float* __restrict__ gb,
                                                 OT* __restrict__ y) {
    __shared__ float sh[4];
    int row = blockIdx.x, t = threadIdx.x;
    float v = x[(size_t)row * kD + t];
    float m = blockReduceSum(v, sh) * (1.0f / kD);
    float dd = v - m;
    float var = blockReduceSum(dd * dd, sh) * (1.0f / (kD - 1));
    float s = sqrtf(var);
    y[(size_t)row * kD + t] = OT(ga[t] * dd / (s + 1e-6f) + gb[t]);
}

// ---------------- bf16 MFMA GEMM: C[M,N] = A[M,256] @ Wt[N,256]^T + bias ----
// MT = rows/64 per block (tile MT*64 x 64). V slot (j==2) of QKV computed
// TRANSPOSED via MFMA operand swap so vt[bh][dk][n] writes coalesce along n.
enum { EPI_QKV = 0, EPI_RESID = 1, EPI_LRELU = 2, EPI_RESID_LRELU = 3 };

template <int EPI, int MT>
__global__ __launch_bounds__(256) void gemm_mfma(const bf16* __restrict__ A,
                                                 const bf16* __restrict__ Wt,
                                                 const float* __restrict__ bias,
                                                 const float* __restrict__ resid,
                                                 void* __restrict__ Cv) {
    __shared__ __align__(16) bf16 As[MT * 64][40];
    __shared__ __align__(16) bf16 Bs[64][40];
    int t = threadIdx.x;
    int m0 = blockIdx.x * (MT * 64), n0 = blockIdx.y * 64;
    int lane = t & 63, w = t >> 6, g = lane >> 4, li = lane & 15;
    const bool vpart = (EPI == EPI_QKV) && (n0 >= 512);   // wave-uniform
    floatx4 zero = {0.f, 0.f, 0.f, 0.f};
    floatx4 acc[MT][4];
    #pragma unroll
    for (int i = 0; i < MT; i++)
        #pragma unroll
        for (int j = 0; j < 4; j++) acc[i][j] = zero;

    for (int k0 = 0; k0 < kD; k0 += 32) {
        int kc = t & 3;
        int r0 = t >> 2;
        #pragma unroll
        for (int i = 0; i < MT; i++)
            *(short8*)&As[r0 + i * 64][kc * 8] =
                *(const short8*)(A + (size_t)(m0 + r0 + i * 64) * kD + k0 + kc * 8);
        *(short8*)&Bs[r0][kc * 8] =
            *(const short8*)(Wt + (size_t)(n0 + r0) * kD + k0 + kc * 8);
        __syncthreads();
        short8 af[MT];
        #pragma unroll
        for (int i = 0; i < MT; i++)
            af[i] = *(const short8*)&As[w * (MT * 16) + i * 16 + li][g * 8];
        if (vpart) {
            #pragma unroll
            for (int ct = 0; ct < 4; ct++) {
                short8 bfr = *(const short8*)&Bs[ct * 16 + li][g * 8];
                #pragma unroll
                for (int i = 0; i < MT; i++)
                    acc[i][ct] = __builtin_amdgcn_mfma_f32_16x16x32_bf16(bfr, af[i], acc[i][ct], 0, 0, 0);
            }
        } else {
            #pragma unroll
            for (int ct = 0; ct < 4; ct++) {
                short8 bfr = *(const short8*)&Bs[ct * 16 + li][g * 8];
                #pragma unroll
                for (int i = 0; i < MT; i++)
                    acc[i][ct] = __builtin_amdgcn_mfma_f32_16x16x32_bf16(af[i], bfr, acc[i][ct], 0, 0, 0);
            }
        }
        __syncthreads();
    }

    if (vpart) {
        // D = C^T tile: D-row = n (weight col), D-col = m (token)
        #pragma unroll
        for (int rt = 0; rt < MT; rt++) {
            #pragma unroll
            for (int ct = 0; ct < 4; ct++) {
                #pragma unroll
                for (int rr = 0; rr < 4; rr++) {
                    int n = n0 + ct * 16 + g * 4 + rr;
                    int m = m0 + w * (MT * 16) + rt * 16 + li;
                    float v = acc[rt][ct][rr] + bias[n];
                    int nn = n & 255;
                    int b = m >> 9, nr = m & 511;
                    int hh = nn >> 5, dk = nn & 31;
                    ((bf16*)Cv)[2 * (size_t)(kB * kN * kD) +
                                (((size_t)(b * kH + hh)) * kDK + dk) * kN + nr] = bf16(v);
                }
            }
        }
        return;
    }

    #pragma unroll
    for (int rt = 0; rt < MT; rt++) {
        #pragma unroll
        for (int ct = 0; ct < 4; ct++) {
            #pragma unroll
            for (int rr = 0; rr < 4; rr++) {
                int m = m0 + w * (MT * 16) + rt * 16 + g * 4 + rr;
                int n = n0 + ct * 16 + li;
                float v = acc[rt][ct][rr] + bias[n];
                if constexpr (EPI == EPI_QKV) {
                    int j = n >> 8, nn = n & 255;
                    int b = m >> 9, nr = m & 511;
                    int hh = nn >> 5, dk = nn & 31;
                    ((bf16*)Cv)[(size_t)j * (kB * kN * kD) +
                                (((size_t)(b * kH + hh)) * kN + nr) * kDK + dk] = bf16(v);
                } else if constexpr (EPI == EPI_RESID) {
                    ((float*)Cv)[(size_t)m * kD + n] = resid[(size_t)m * kD + n] + v;
                } else if constexpr (EPI == EPI_LRELU) {
                    ((bf16*)Cv)[(size_t)m * kD + n] = bf16(v > 0.f ? v : 0.1f * v);
                } else {
                    float lv = v > 0.f ? v : 0.1f * v;
                    ((float*)Cv)[(size_t)m * kD + n] = resid[(size_t)m * kD + n] + lv;
                }
            }
        }
    }
}

// ---------------- pcV = pc[b] (512x512) @ V[b] (512x256) -> attb ------------
// B-operand rows are vt[b] = [256 features][512 tokens] (already B^T layout).
__global__ __launch_bounds__(256) void pcv_gemm(const bf16* __restrict__ pcb,
                                                const bf16* __restrict__ vtb,
                                                bf16* __restrict__ attb) {
    __shared__ __align__(16) bf16 As[128][40];
    __shared__ __align__(16) bf16 Bs[64][40];
    int t = threadIdx.x;
    int m0 = blockIdx.x * 128, n0 = blockIdx.y * 64, b = blockIdx.z;
    int lane = t & 63, w = t >> 6, g = lane >> 4, li = lane & 15;
    floatx4 zero = {0.f, 0.f, 0.f, 0.f};
    floatx4 acc[2][4];
    #pragma unroll
    for (int i = 0; i < 2; i++)
        #pragma unroll
        for (int j = 0; j < 4; j++) acc[i][j] = zero;

    const bf16* Abase = pcb + (size_t)b * kN * kN;   // [512][512]
    const bf16* Bbase = vtb + (size_t)b * kD * kN;   // [256][512]
    for (int k0 = 0; k0 < kN; k0 += 32) {
        int kc = t & 3;
        int r0 = t >> 2;
        *(short8*)&As[r0][kc * 8] =
            *(const short8*)(Abase + (size_t)(m0 + r0) * kN + k0 + kc * 8);
        *(short8*)&As[r0 + 64][kc * 8] =
            *(const short8*)(Abase + (size_t)(m0 + r0 + 64) * kN + k0 + kc * 8);
        *(short8*)&Bs[r0][kc * 8] =
            *(const short8*)(Bbase + (size_t)(n0 + r0) * kN + k0 + kc * 8);
        __syncthreads();
        short8 af0 = *(const short8*)&As[w * 32 + li][g * 8];
        short8 af1 = *(const short8*)&As[w * 32 + 16 + li][g * 8];
        #pragma unroll
        for (int ct = 0; ct < 4; ct++) {
            short8 bfr = *(const short8*)&Bs[ct * 16 + li][g * 8];
            acc[0][ct] = __builtin_amdgcn_mfma_f32_16x16x32_bf16(af0, bfr, acc[0][ct], 0, 0, 0);
            acc[1][ct] = __builtin_amdgcn_mfma_f32_16x16x32_bf16(af1, bfr, acc[1][ct], 0, 0, 0);
        }
        __syncthreads();
    }

    #pragma unroll
    for (int rt = 0; rt < 2; rt++) {
        #pragma unroll
        for (int ct = 0; ct < 4; ct++) {
            #pragma unroll
            for (int rr = 0; rr < 4; rr++) {
                int m = m0 + w * 32 + rt * 16 + g * 4 + rr;
                int n = n0 + ct * 16 + li;
                attb[((size_t)b * kN + m) * kD + n] = bf16(acc[rt][ct][rr]);
            }
        }
    }
}

// ---------------- MFMA attention (barrier-free, per-wave; 4 waves/block) ----
// att^T = V^T @ P^T; accumulates (RMW) onto attb which pcv_gemm pre-filled
// with the pc@V term.
__global__ __launch_bounds__(256, 2) void attn_mfma(const bf16* __restrict__ qb,
                                                    const bf16* __restrict__ kb,
                                                    const bf16* __restrict__ vtb,
                                                    const unsigned* __restrict__ mp,
                                                    bf16* __restrict__ att) {
    __shared__ __align__(16) bf16 Pbuf[4][16][136];   // 17.4 KB, per-wave chunks

    int blk = blockIdx.x;
    int qt = blk & 7;
    int bh = blk >> 3;
    int b = bh >> 3;
    int h = bh & 7;
    int t = threadIdx.x;
    int lane = t & 63, w = t >> 6;
    int g = lane >> 4, li = lane & 15;

    // ---- scores: S = Q @ K^T (one wave: 16 q-rows x 512 cols) ----
    const bf16* qrow = qb + ((size_t)bh * kN + qt * 64 + w * 16 + li) * kDK + g * 8;
    short8 aQ = *(const short8*)qrow;
    const bf16* kbase = kb + (size_t)bh * kN * kDK;
    unsigned mbits = mp[b * 16 + li];

    floatx4 s[32];
    floatx4 zero = {0.f, 0.f, 0.f, 0.f};
    #pragma unroll
    for (int tt = 0; tt < 32; tt++) {
        short8 bK = *(const short8*)(kbase + (size_t)(tt * 16 + li) * kDK + g * 8);
        s[tt] = __builtin_amdgcn_mfma_f32_16x16x32_bf16(aQ, bK, zero, 0, 0, 0);
    }

    const float scale = 0.17677669529663689f;  // 1/sqrt(32)
    #pragma unroll
    for (int tt = 0; tt < 32; tt++) {
        bool mm = (mbits >> tt) & 1;
        #pragma unroll
        for (int r = 0; r < 4; r++)
            s[tt][r] = mm ? s[tt][r] * scale : -1e12f;
    }

    // ---- softmax per row (row = g*4 + r; cols spread over li and tt) ----
    #pragma unroll
    for (int r = 0; r < 4; r++) {
        float mx = s[0][r];
        #pragma unroll
        for (int tt = 1; tt < 32; tt++) mx = fmaxf(mx, s[tt][r]);
        #pragma unroll
        for (int o = 1; o < 16; o <<= 1) mx = fmaxf(mx, __shfl_xor(mx, o, 64));
        float sum = 0.f;
        #pragma unroll
        for (int tt = 0; tt < 32; tt++) {
            float e = __expf(s[tt][r] - mx);
            s[tt][r] = e;
            sum += e;
        }
        #pragma unroll
        for (int o = 1; o < 16; o <<= 1) sum += __shfl_xor(sum, o, 64);
        float inv = 0.3f / sum;
        #pragma unroll
        for (int tt = 0; tt < 32; tt++) s[tt][r] *= inv;
    }

    // ---- PV: att^T += VT @ P^T, chunked transpose through LDS ----
    bf16* pb = &Pbuf[w][0][0];
    const bf16* vt = vtb + (size_t)bh * kDK * kN;       // [32][512]
    floatx4 accA0 = zero, accA1 = zero;
    #pragma unroll
    for (int c = 0; c < 4; c++) {
        #pragma unroll
        for (int ttl = 0; ttl < 8; ttl++) {
            int tt = c * 8 + ttl;
            int kcol = ttl * 16 + li;
            #pragma unroll
            for (int r = 0; r < 4; r++)
                pb[(g * 4 + r) * 136 + kcol] = bf16(s[tt][r]);
        }
        #pragma unroll
        for (int k2 = 0; k2 < 4; k2++) {
            int soff = c * 128 + k2 * 32 + g * 8;
            short8 aP  = *(const short8*)(pb + li * 136 + k2 * 32 + g * 8);
            short8 aV0 = *(const short8*)(vt + (size_t)li * kN + soff);
            short8 aV1 = *(const short8*)(vt + (size_t)(16 + li) * kN + soff);
            accA0 = __builtin_amdgcn_mfma_f32_16x16x32_bf16(aV0, aP, accA0, 0, 0, 0);
            accA1 = __builtin_amdgcn_mfma_f32_16x16x32_bf16(aV1, aP, accA1, 0, 0, 0);
        }
    }

    // ---- epilogue: RMW add onto pcV; rows = dk (g*4+r), cols = q (li) ----
    size_t row = (size_t)b * kN + qt * 64 + w * 16 + li;
    bf16* arow = att + row * kD + h * kDK;
    union { short s4[4]; bf16 h4[4]; } e0, e1, p0, p1;
    *(short4*)e0.s4 = *(const short4*)(arow + g * 4);
    *(short4*)e1.s4 = *(const short4*)(arow + 16 + g * 4);
    #pragma unroll
    for (int r = 0; r < 4; r++) {
        p0.h4[r] = bf16(accA0[r] + (float)e0.h4[r]);
        p1.h4[r] = bf16(accA1[r] + (float)e1.h4[r]);
    }
    *(short4*)(arow + g * 4)      = *(short4*)p0.s4;
    *(short4*)(arow + 16 + g * 4) = *(short4*)p1.s4;
}

// ---------------- host launcher --------------------------------------------
extern "C" void kernel_launch(void* const* d_in, const int* in_sizes, int n_in,
                              void* d_out, int out_size, void* d_ws, size_t ws_size,
                              hipStream_t stream) {
    const float* x    = (const float*)d_in[0];
    const int*   mask = (const int*)d_in[1];
    const float* adj  = (const float*)d_in[2];
    const float* dist = (const float*)d_in[3];
    const float* Wq = (const float*)d_in[5];  const float* bq = (const float*)d_in[6];
    const float* Wk = (const float*)d_in[7];  const float* bk = (const float*)d_in[8];
    const float* Wv = (const float*)d_in[9];  const float* bv = (const float*)d_in[10];
    const float* Wo = (const float*)d_in[11]; const float* bo = (const float*)d_in[12];
    const float* Wf1 = (const float*)d_in[13]; const float* bf1 = (const float*)d_in[14];
    const float* Wf2 = (const float*)d_in[15]; const float* bf2 = (const float*)d_in[16];
    const float* ln1a = (const float*)d_in[17]; const float* ln1b = (const float*)d_in[18];
    const float* ln2a = (const float*)d_in[19]; const float* ln2b = (const float*)d_in[20];
    const float* lnfa = (const float*)d_in[21]; const float* lnfb = (const float*)d_in[22];

    const size_t rows = (size_t)kB * kN;          // 8192
    const size_t actN = rows * kD;                // 2,097,152 elems

    char* wsb = (char*)d_ws;
    bf16*  pcb   = (bf16*)wsb;  wsb += (size_t)kB * kN * kN * sizeof(bf16);
    float* xc    = (float*)wsb; wsb += actN * sizeof(float);
    bf16*  h     = (bf16*)wsb;  wsb += actN * sizeof(bf16);
    bf16*  h2    = (bf16*)wsb;  wsb += actN * sizeof(bf16);
    bf16*  attb  = (bf16*)wsb;  wsb += actN * sizeof(bf16);
    bf16*  qkvb  = (bf16*)wsb;  wsb += 3 * actN * sizeof(bf16);
    bf16*  wqkv  = (bf16*)wsb;  wsb += (size_t)kL * 768 * kD * sizeof(bf16);
    bf16*  wo_t  = (bf16*)wsb;  wsb += (size_t)kL * kD * kD * sizeof(bf16);
    bf16*  wf1_t = (bf16*)wsb;  wsb += (size_t)kL * kD * kD * sizeof(bf16);
    bf16*  wf2_t = (bf16*)wsb;  wsb += (size_t)kL * kD * kD * sizeof(bf16);
    float* bcat  = (float*)wsb; wsb += (size_t)kL * 768 * sizeof(float);
    unsigned* mpk = (unsigned*)wsb; wsb += 256 * sizeof(unsigned);

    hipMemcpyAsync(xc, x, actN * sizeof(float), hipMemcpyDeviceToDevice, stream);
    wconv_kernel<<<24 * 64, 256, 0, stream>>>(Wq, Wk, Wv, Wo, Wf1, Wf2, wqkv, wo_t, wf1_t, wf2_t);
    bcat_kernel<<<kL * 768 / 256, 256, 0, stream>>>(bq, bk, bv, bcat);
    mpack_kernel<<<1, 256, 0, stream>>>(mask, mpk);
    pc_kernel<<<kB * kN, 256, 0, stream>>>(adj, dist, mask, pcb);

    dim3 gQKV(64, 12);    // (8192/128) x (768/64), MT=2
    dim3 g256(128, 4);    // (8192/64)  x (256/64), MT=1
    dim3 gPCV(4, 4, kB);  // (512/128) x (256/64) x B
    for (int i = 0; i < kL; i++) {
        const size_t bOff = (size_t)i * kD;
        ln_kernel<bf16><<<rows, 256, 0, stream>>>(xc, ln1a + bOff, ln1b + bOff, h);
        gemm_mfma<EPI_QKV, 2><<<gQKV, 256, 0, stream>>>(h, wqkv + (size_t)i * 768 * kD,
                                                        bcat + (size_t)i * 768, nullptr, qkvb);
        pcv_gemm<<<gPCV, 256, 0, stream>>>(pcb, qkvb + 2 * actN, attb);
        attn_mfma<<<kB * kH * (kN / 64), 256, 0, stream>>>(qkvb, qkvb + actN, qkvb + 2 * actN,
                                                           mpk, attb);
        gemm_mfma<EPI_RESID, 1><<<g256, 256, 0, stream>>>(attb, wo_t + (size_t)i * kD * kD,
                                                          bo + bOff, xc, xc);
        ln_kernel<bf16><<<rows, 256, 0, stream>>>(xc, ln2a + bOff, ln2b + bOff, h);
        gemm_mfma<EPI_LRELU, 1><<<g256, 256, 0, stream>>>(h, wf1_t + (size_t)i * kD * kD,
                                                          bf1 + bOff, nullptr, h2);
        gemm_mfma<EPI_RESID_LRELU, 1><<<g256, 256, 0, stream>>>(h2, wf2_t + (size_t)i * kD * kD,
                                                                bf2 + bOff, xc, xc);
    }
    ln_kernel<float><<<rows, 256, 0, stream>>>(xc, lnfa, lnfb, (float*)d_out);
}

// Round 8
// 494.591 us; speedup vs baseline: 1.0568x; 1.0568x over previous
//
#include <hip/hip_runtime.h>
#include <hip/hip_bf16.h>
#include <math.h>

// Problem constants (from reference)
constexpr int kB  = 16;
constexpr int kN  = 512;
constexpr int kD  = 256;
constexpr int kH  = 8;
constexpr int kDK = 32;
constexpr int kL  = 4;

using bf16 = __hip_bfloat16;
using short8 = __attribute__((ext_vector_type(8))) short;   // 8 bf16 = 4 VGPR
using floatx4 = __attribute__((ext_vector_type(4))) float;  // MFMA C/D frag

// ---------------- block reduction helpers (256 threads = 4 waves) ----------
__device__ __forceinline__ float blockReduceSum(float v, float* sh) {
    #pragma unroll
    for (int o = 32; o > 0; o >>= 1) v += __shfl_down(v, o, 64);
    int lane = threadIdx.x & 63, w = threadIdx.x >> 6;
    __syncthreads();
    if (lane == 0) sh[w] = v;
    __syncthreads();
    return sh[0] + sh[1] + sh[2] + sh[3];
}

__device__ __forceinline__ float blockReduceMax(float v, float* sh) {
    #pragma unroll
    for (int o = 32; o > 0; o >>= 1) v = fmaxf(v, __shfl_down(v, o, 64));
    int lane = threadIdx.x & 63, w = threadIdx.x >> 6;
    __syncthreads();
    if (lane == 0) sh[w] = v;
    __syncthreads();
    return fmaxf(fmaxf(sh[0], sh[1]), fmaxf(sh[2], sh[3]));
}

// ---------------- weight transpose+convert: W[k][n] fp32 -> Wt[n][k] bf16 ---
__global__ __launch_bounds__(256) void wconv_kernel(const float* __restrict__ Wq,
                                                    const float* __restrict__ Wk,
                                                    const float* __restrict__ Wv,
                                                    const float* __restrict__ Wo,
                                                    const float* __restrict__ Wf1,
                                                    const float* __restrict__ Wf2,
                                                    bf16* __restrict__ wqkv,
                                                    bf16* __restrict__ wo,
                                                    bf16* __restrict__ wf1,
                                                    bf16* __restrict__ wf2) {
    __shared__ float tile[32][33];
    int bid = blockIdx.x;            // 24 * 64
    int mat = bid >> 6;
    int t6 = bid & 63;
    int tr = t6 >> 3, tc = t6 & 7;
    int layer = mat / 6, slot = mat % 6;
    const float* src =
        slot == 0 ? Wq : slot == 1 ? Wk : slot == 2 ? Wv :
        slot == 3 ? Wo : slot == 4 ? Wf1 : Wf2;
    src += (size_t)layer * kD * kD;
    bf16* dst;
    if (slot < 3) dst = wqkv + ((size_t)layer * 768 + slot * 256) * kD;
    else dst = (slot == 3 ? wo : slot == 4 ? wf1 : wf2) + (size_t)layer * kD * kD;
    int t = threadIdx.x;
    int r = t >> 5, c = t & 31;
    #pragma unroll
    for (int i = 0; i < 4; i++)
        tile[r + i * 8][c] = src[(size_t)(tr * 32 + r + i * 8) * kD + tc * 32 + c];
    __syncthreads();
    #pragma unroll
    for (int i = 0; i < 4; i++)
        dst[(size_t)(tc * 32 + r + i * 8) * kD + tr * 32 + c] = bf16(tile[c][r + i * 8]);
}

// ---------------- bias concat for QKV ---------------------------------------
__global__ __launch_bounds__(256) void bcat_kernel(const float* __restrict__ bq,
                                                   const float* __restrict__ bk,
                                                   const float* __restrict__ bv,
                                                   float* __restrict__ bcat) {
    int idx = blockIdx.x * 256 + threadIdx.x;
    int layer = idx / 768, j = idx % 768;
    const float* s = j < 256 ? bq : j < 512 ? bk : bv;
    bcat[idx] = s[layer * 256 + (j & 255)];
}

// ---------------- packed column mask: mpack[b][li] bit tt = mask[b][tt*16+li]
__global__ __launch_bounds__(256) void mpack_kernel(const int* __restrict__ mask,
                                                    unsigned* __restrict__ mp) {
    int t = threadIdx.x;            // 1 block of 256: b = t>>4, li = t&15
    int b = t >> 4, li = t & 15;
    unsigned bits = 0;
    #pragma unroll
    for (int tt = 0; tt < 32; tt++)
        bits |= (unsigned)(mask[b * kN + tt * 16 + li] != 0) << tt;
    mp[t] = bits;
}

// ---------------- pc = 0.3*softmax(mask? -dist : -inf) + 0.4*adj/rowsum ----
__global__ __launch_bounds__(256) void pc_kernel(const float* __restrict__ adj,
                                                 const float* __restrict__ dist,
                                                 const int* __restrict__ mask,
                                                 bf16* __restrict__ pcb) {
    __shared__ float sh[4];
    int row = blockIdx.x;
    int b = row >> 9;
    int t = threadIdx.x;
    const float* dr = dist + (size_t)row * kN;
    const float* ar = adj + (size_t)row * kN;
    const int* mr = mask + b * kN;
    float d0 = dr[t], d1 = dr[t + 256];
    float a0 = ar[t], a1 = ar[t + 256];
    int m0 = mr[t], m1 = mr[t + 256];
    float s0 = m0 ? -d0 : -INFINITY;
    float s1 = m1 ? -d1 : -INFINITY;
    float mx = blockReduceMax(fmaxf(s0, s1), sh);
    float e0 = __expf(s0 - mx);
    float e1 = __expf(s1 - mx);
    float sum  = blockReduceSum(e0 + e1, sh);
    float asum = blockReduceSum(a0 + a1, sh);
    float w_d = 0.3f / sum;
    float w_a = 0.4f / (asum + 1e-6f);
    bf16* pr = pcb + (size_t)row * kN;
    pr[t]       = bf16(e0 * w_d + a0 * w_a);
    pr[t + 256] = bf16(e1 * w_d + a1 * w_a);
}

// ---------------- initial: xc = x copy; h = LN1_0(x) bf16 -------------------
__global__ __launch_bounds__(256) void ln_init(const float* __restrict__ x,
                                               const float* __restrict__ ga,
                                               const float* __restrict__ gb,
                                               float* __restrict__ xc,
                                               bf16* __restrict__ h) {
    __shared__ float sh[4];
    int row = blockIdx.x, t = threadIdx.x;
    float v = x[(size_t)row * kD + t];
    xc[(size_t)row * kD + t] = v;
    float m = blockReduceSum(v, sh) * (1.0f / kD);
    float dd = v - m;
    float var = blockReduceSum(dd * dd, sh) * (1.0f / (kD - 1));
    float s = sqrtf(var);
    h[(size_t)row * kD + t] = bf16(ga[t] * dd / (s + 1e-6f) + gb[t]);
}

// ---------------- bf16 MFMA GEMM: C[M,N] = A[M,256] @ Wt[N,256]^T + bias ----
// MT = rows/64 per block (tile MT*64 x 64). V slot (j==2) of QKV computed
// TRANSPOSED via MFMA operand swap so vt[bh][dk][n] writes coalesce along n.
enum { EPI_QKV = 0, EPI_LRELU = 2 };

template <int EPI, int MT>
__global__ __launch_bounds__(256) void gemm_mfma(const bf16* __restrict__ A,
                                                 const bf16* __restrict__ Wt,
                                                 const float* __restrict__ bias,
                                                 void* __restrict__ Cv) {
    __shared__ __align__(16) bf16 As[MT * 64][40];
    __shared__ __align__(16) bf16 Bs[64][40];
    int t = threadIdx.x;
    int m0 = blockIdx.x * (MT * 64), n0 = blockIdx.y * 64;
    int lane = t & 63, w = t >> 6, g = lane >> 4, li = lane & 15;
    const bool vpart = (EPI == EPI_QKV) && (n0 >= 512);   // wave-uniform
    floatx4 zero = {0.f, 0.f, 0.f, 0.f};
    floatx4 acc[MT][4];
    #pragma unroll
    for (int i = 0; i < MT; i++)
        #pragma unroll
        for (int j = 0; j < 4; j++) acc[i][j] = zero;

    for (int k0 = 0; k0 < kD; k0 += 32) {
        int kc = t & 3;
        int r0 = t >> 2;
        #pragma unroll
        for (int i = 0; i < MT; i++)
            *(short8*)&As[r0 + i * 64][kc * 8] =
                *(const short8*)(A + (size_t)(m0 + r0 + i * 64) * kD + k0 + kc * 8);
        *(short8*)&Bs[r0][kc * 8] =
            *(const short8*)(Wt + (size_t)(n0 + r0) * kD + k0 + kc * 8);
        __syncthreads();
        short8 af[MT];
        #pragma unroll
        for (int i = 0; i < MT; i++)
            af[i] = *(const short8*)&As[w * (MT * 16) + i * 16 + li][g * 8];
        if (vpart) {
            #pragma unroll
            for (int ct = 0; ct < 4; ct++) {
                short8 bfr = *(const short8*)&Bs[ct * 16 + li][g * 8];
                #pragma unroll
                for (int i = 0; i < MT; i++)
                    acc[i][ct] = __builtin_amdgcn_mfma_f32_16x16x32_bf16(bfr, af[i], acc[i][ct], 0, 0, 0);
            }
        } else {
            #pragma unroll
            for (int ct = 0; ct < 4; ct++) {
                short8 bfr = *(const short8*)&Bs[ct * 16 + li][g * 8];
                #pragma unroll
                for (int i = 0; i < MT; i++)
                    acc[i][ct] = __builtin_amdgcn_mfma_f32_16x16x32_bf16(af[i], bfr, acc[i][ct], 0, 0, 0);
            }
        }
        __syncthreads();
    }

    if (vpart) {
        // D = C^T tile: D-row = n (weight col), D-col = m (token)
        #pragma unroll
        for (int rt = 0; rt < MT; rt++) {
            #pragma unroll
            for (int ct = 0; ct < 4; ct++) {
                #pragma unroll
                for (int rr = 0; rr < 4; rr++) {
                    int n = n0 + ct * 16 + g * 4 + rr;
                    int m = m0 + w * (MT * 16) + rt * 16 + li;
                    float v = acc[rt][ct][rr] + bias[n];
                    int nn = n & 255;
                    int b = m >> 9, nr = m & 511;
                    int hh = nn >> 5, dk = nn & 31;
                    ((bf16*)Cv)[2 * (size_t)(kB * kN * kD) +
                                (((size_t)(b * kH + hh)) * kDK + dk) * kN + nr] = bf16(v);
                }
            }
        }
        return;
    }

    #pragma unroll
    for (int rt = 0; rt < MT; rt++) {
        #pragma unroll
        for (int ct = 0; ct < 4; ct++) {
            #pragma unroll
            for (int rr = 0; rr < 4; rr++) {
                int m = m0 + w * (MT * 16) + rt * 16 + g * 4 + rr;
                int n = n0 + ct * 16 + li;
                float v = acc[rt][ct][rr] + bias[n];
                if constexpr (EPI == EPI_QKV) {
                    int j = n >> 8, nn = n & 255;
                    int b = m >> 9, nr = m & 511;
                    int hh = nn >> 5, dk = nn & 31;
                    ((bf16*)Cv)[(size_t)j * (kB * kN * kD) +
                                (((size_t)(b * kH + hh)) * kN + nr) * kDK + dk] = bf16(v);
                } else {   // EPI_LRELU
                    ((bf16*)Cv)[(size_t)m * kD + n] = bf16(v > 0.f ? v : 0.1f * v);
                }
            }
        }
    }
}

// ---------------- full-row GEMM + residual + fused LayerNorm ---------------
// Tile 64 x 256 (full N). FEPI 0: v = resid + (acc+bias)          (Wo path)
//                         FEPI 1: v = resid + lrelu(acc+bias)     (F2 path)
// last==0: write xcOut = v (fp32) and hOut = bf16(LN(v))
// last==1: write outF32 = LN(v) (fp32) only
template <int FEPI>
__global__ __launch_bounds__(256) void gemm_nfull(const bf16* __restrict__ A,
                                                  const bf16* __restrict__ Wt,
                                                  const float* __restrict__ bias,
                                                  const float* __restrict__ resid,
                                                  const float* __restrict__ ga,
                                                  const float* __restrict__ gb,
                                                  float* __restrict__ xcOut,
                                                  bf16* __restrict__ hOut,
                                                  float* __restrict__ outF32,
                                                  int last) {
    __shared__ __align__(16) bf16 As[64][40];
    __shared__ __align__(16) bf16 Bs[256][40];
    int t = threadIdx.x;
    int m0 = blockIdx.x * 64;
    int lane = t & 63, w = t >> 6, g = lane >> 4, li = lane & 15;
    floatx4 zero = {0.f, 0.f, 0.f, 0.f};
    floatx4 acc[16];
    #pragma unroll
    for (int ct = 0; ct < 16; ct++) acc[ct] = zero;

    for (int k0 = 0; k0 < kD; k0 += 32) {
        int kc = t & 3;
        int r0 = t >> 2;
        *(short8*)&As[r0][kc * 8] =
            *(const short8*)(A + (size_t)(m0 + r0) * kD + k0 + kc * 8);
        #pragma unroll
        for (int i = 0; i < 4; i++) {
            int slot = t + i * 256;              // 1024 slots = 256 rows x 4
            int rr = slot >> 2, kc2 = slot & 3;
            *(short8*)&Bs[rr][kc2 * 8] =
                *(const short8*)(Wt + (size_t)rr * kD + k0 + kc2 * 8);
        }
        __syncthreads();
        short8 af = *(const short8*)&As[w * 16 + li][g * 8];
        #pragma unroll
        for (int ct = 0; ct < 16; ct++) {
            short8 bfr = *(const short8*)&Bs[ct * 16 + li][g * 8];
            acc[ct] = __builtin_amdgcn_mfma_f32_16x16x32_bf16(af, bfr, acc[ct], 0, 0, 0);
        }
        __syncthreads();
    }

    // epilogue: v (in place in acc) = resid + (FEPI? lrelu(acc+bias) : acc+bias)
    int mbase = m0 + w * 16 + g * 4;
    #pragma unroll
    for (int ct = 0; ct < 16; ct++) {
        int n = ct * 16 + li;
        float bb = bias[n];
        #pragma unroll
        for (int rr = 0; rr < 4; rr++) {
            float v = acc[ct][rr] + bb;
            if (FEPI == 1) v = v > 0.f ? v : 0.1f * v;
            v += resid[(size_t)(mbase + rr) * kD + n];
            acc[ct][rr] = v;
        }
    }
    // per-row LN stats (row = mbase+rr; cols over ct and li)
    float mean[4], scl[4];
    #pragma unroll
    for (int rr = 0; rr < 4; rr++) {
        float s1 = 0.f, s2 = 0.f;
        #pragma unroll
        for (int ct = 0; ct < 16; ct++) {
            float xv = acc[ct][rr];
            s1 += xv;
            s2 += xv * xv;
        }
        #pragma unroll
        for (int o = 1; o < 16; o <<= 1) {
            s1 += __shfl_xor(s1, o, 64);
            s2 += __shfl_xor(s2, o, 64);
        }
        float mn = s1 * (1.0f / kD);
        float var = (s2 - (float)kD * mn * mn) * (1.0f / (kD - 1));
        var = fmaxf(var, 0.f);
        mean[rr] = mn;
        scl[rr] = 1.0f / (sqrtf(var) + 1e-6f);
    }
    if (!last) {
        #pragma unroll
        for (int ct = 0; ct < 16; ct++) {
            int n = ct * 16 + li;
            float gaa = ga[n], gbb = gb[n];
            #pragma unroll
            for (int rr = 0; rr < 4; rr++) {
                size_t idx = (size_t)(mbase + rr) * kD + n;
                float v = acc[ct][rr];
                xcOut[idx] = v;
                hOut[idx] = bf16(gaa * (v - mean[rr]) * scl[rr] + gbb);
            }
        }
    } else {
        #pragma unroll
        for (int ct = 0; ct < 16; ct++) {
            int n = ct * 16 + li;
            float gaa = ga[n], gbb = gb[n];
            #pragma unroll
            for (int rr = 0; rr < 4; rr++) {
                size_t idx = (size_t)(mbase + rr) * kD + n;
                float v = acc[ct][rr];
                outF32[idx] = gaa * (v - mean[rr]) * scl[rr] + gbb;
            }
        }
    }
}

// ---------------- pcV = pc[b] (512x512) @ V[b] (512x256) -> attb ------------
// Tile 64 x 128, grid (8, 2, 16): pc read only 2x per layer.
__global__ __launch_bounds__(256) void pcv_gemm(const bf16* __restrict__ pcb,
                                                const bf16* __restrict__ vtb,
                                                bf16* __restrict__ attb) {
    __shared__ __align__(16) bf16 As[64][40];
    __shared__ __align__(16) bf16 Bs[128][40];
    int t = threadIdx.x;
    int m0 = blockIdx.x * 64, n0 = blockIdx.y * 128, b = blockIdx.z;
    int lane = t & 63, w = t >> 6, g = lane >> 4, li = lane & 15;
    floatx4 zero = {0.f, 0.f, 0.f, 0.f};
    floatx4 acc[8];
    #pragma unroll
    for (int ct = 0; ct < 8; ct++) acc[ct] = zero;

    const bf16* Abase = pcb + (size_t)b * kN * kN;   // [512][512]
    const bf16* Bbase = vtb + (size_t)b * kD * kN;   // [256][512]
    for (int k0 = 0; k0 < kN; k0 += 32) {
        int kc = t & 3;
        int r0 = t >> 2;
        *(short8*)&As[r0][kc * 8] =
            *(const short8*)(Abase + (size_t)(m0 + r0) * kN + k0 + kc * 8);
        #pragma unroll
        for (int i = 0; i < 2; i++) {
            int slot = t + i * 256;              // 512 slots = 128 rows x 4
            int rr = slot >> 2, kc2 = slot & 3;
            *(short8*)&Bs[rr][kc2 * 8] =
                *(const short8*)(Bbase + (size_t)(n0 + rr) * kN + k0 + kc2 * 8);
        }
        __syncthreads();
        short8 af = *(const short8*)&As[w * 16 + li][g * 8];
        #pragma unroll
        for (int ct = 0; ct < 8; ct++) {
            short8 bfr = *(const short8*)&Bs[ct * 16 + li][g * 8];
            acc[ct] = __builtin_amdgcn_mfma_f32_16x16x32_bf16(af, bfr, acc[ct], 0, 0, 0);
        }
        __syncthreads();
    }

    #pragma unroll
    for (int ct = 0; ct < 8; ct++) {
        #pragma unroll
        for (int rr = 0; rr < 4; rr++) {
            int m = m0 + w * 16 + g * 4 + rr;
            int n = n0 + ct * 16 + li;
            attb[((size_t)b * kN + m) * kD + n] = bf16(acc[ct][rr]);
        }
    }
}

// ---------------- MFMA attention (barrier-free, per-wave; 4 waves/block) ----
// att^T = V^T @ P^T; accumulates (RMW) onto attb which pcv_gemm pre-filled
// with the pc@V term.
__global__ __launch_bounds__(256, 2) void attn_mfma(const bf16* __restrict__ qb,
                                                    const bf16* __restrict__ kb,
                                                    const bf16* __restrict__ vtb,
                                                    const unsigned* __restrict__ mp,
                                                    bf16* __restrict__ att) {
    __shared__ __align__(16) bf16 Pbuf[4][16][136];   // 17.4 KB, per-wave chunks

    int blk = blockIdx.x;
    int qt = blk & 7;
    int bh = blk >> 3;
    int b = bh >> 3;
    int h = bh & 7;
    int t = threadIdx.x;
    int lane = t & 63, w = t >> 6;
    int g = lane >> 4, li = lane & 15;

    // ---- scores: S = Q @ K^T (one wave: 16 q-rows x 512 cols) ----
    const bf16* qrow = qb + ((size_t)bh * kN + qt * 64 + w * 16 + li) * kDK + g * 8;
    short8 aQ = *(const short8*)qrow;
    const bf16* kbase = kb + (size_t)bh * kN * kDK;
    unsigned mbits = mp[b * 16 + li];

    floatx4 s[32];
    floatx4 zero = {0.f, 0.f, 0.f, 0.f};
    #pragma unroll
    for (int tt = 0; tt < 32; tt++) {
        short8 bK = *(const short8*)(kbase + (size_t)(tt * 16 + li) * kDK + g * 8);
        s[tt] = __builtin_amdgcn_mfma_f32_16x16x32_bf16(aQ, bK, zero, 0, 0, 0);
    }

    const float scale = 0.17677669529663689f;  // 1/sqrt(32)
    #pragma unroll
    for (int tt = 0; tt < 32; tt++) {
        bool mm = (mbits >> tt) & 1;
        #pragma unroll
        for (int r = 0; r < 4; r++)
            s[tt][r] = mm ? s[tt][r] * scale : -1e12f;
    }

    // ---- softmax per row (row = g*4 + r; cols spread over li and tt) ----
    #pragma unroll
    for (int r = 0; r < 4; r++) {
        float mx = s[0][r];
        #pragma unroll
        for (int tt = 1; tt < 32; tt++) mx = fmaxf(mx, s[tt][r]);
        #pragma unroll
        for (int o = 1; o < 16; o <<= 1) mx = fmaxf(mx, __shfl_xor(mx, o, 64));
        float sum = 0.f;
        #pragma unroll
        for (int tt = 0; tt < 32; tt++) {
            float e = __expf(s[tt][r] - mx);
            s[tt][r] = e;
            sum += e;
        }
        #pragma unroll
        for (int o = 1; o < 16; o <<= 1) sum += __shfl_xor(sum, o, 64);
        float inv = 0.3f / sum;
        #pragma unroll
        for (int tt = 0; tt < 32; tt++) s[tt][r] *= inv;
    }

    // ---- PV: att^T += VT @ P^T, chunked transpose through LDS ----
    bf16* pb = &Pbuf[w][0][0];
    const bf16* vt = vtb + (size_t)bh * kDK * kN;       // [32][512]
    floatx4 accA0 = zero, accA1 = zero;
    #pragma unroll
    for (int c = 0; c < 4; c++) {
        #pragma unroll
        for (int ttl = 0; ttl < 8; ttl++) {
            int tt = c * 8 + ttl;
            int kcol = ttl * 16 + li;
            #pragma unroll
            for (int r = 0; r < 4; r++)
                pb[(g * 4 + r) * 136 + kcol] = bf16(s[tt][r]);
        }
        #pragma unroll
        for (int k2 = 0; k2 < 4; k2++) {
            int soff = c * 128 + k2 * 32 + g * 8;
            short8 aP  = *(const short8*)(pb + li * 136 + k2 * 32 + g * 8);
            short8 aV0 = *(const short8*)(vt + (size_t)li * kN + soff);
            short8 aV1 = *(const short8*)(vt + (size_t)(16 + li) * kN + soff);
            accA0 = __builtin_amdgcn_mfma_f32_16x16x32_bf16(aV0, aP, accA0, 0, 0, 0);
            accA1 = __builtin_amdgcn_mfma_f32_16x16x32_bf16(aV1, aP, accA1, 0, 0, 0);
        }
    }

    // ---- epilogue: RMW add onto pcV; rows = dk (g*4+r), cols = q (li) ----
    size_t row = (size_t)b * kN + qt * 64 + w * 16 + li;
    bf16* arow = att + row * kD + h * kDK;
    union { short s4[4]; bf16 h4[4]; } e0, e1, p0, p1;
    *(short4*)e0.s4 = *(const short4*)(arow + g * 4);
    *(short4*)e1.s4 = *(const short4*)(arow + 16 + g * 4);
    #pragma unroll
    for (int r = 0; r < 4; r++) {
        p0.h4[r] = bf16(accA0[r] + (float)e0.h4[r]);
        p1.h4[r] = bf16(accA1[r] + (float)e1.h4[r]);
    }
    *(short4*)(arow + g * 4)      = *(short4*)p0.s4;
    *(short4*)(arow + 16 + g * 4) = *(short4*)p1.s4;
}

// ---------------- host launcher --------------------------------------------
extern "C" void kernel_launch(void* const* d_in, const int* in_sizes, int n_in,
                              void* d_out, int out_size, void* d_ws, size_t ws_size,
                              hipStream_t stream) {
    const float* x    = (const float*)d_in[0];
    const int*   mask = (const int*)d_in[1];
    const float* adj  = (const float*)d_in[2];
    const float* dist = (const float*)d_in[3];
    const float* Wq = (const float*)d_in[5];  const float* bq = (const float*)d_in[6];
    const float* Wk = (const float*)d_in[7];  const float* bk = (const float*)d_in[8];
    const float* Wv = (const float*)d_in[9];  const float* bv = (const float*)d_in[10];
    const float* Wo = (const float*)d_in[11]; const float* bo = (const float*)d_in[12];
    const float* Wf1 = (const float*)d_in[13]; const float* bf1 = (const float*)d_in[14];
    const float* Wf2 = (const float*)d_in[15]; const float* bf2 = (const float*)d_in[16];
    const float* ln1a = (const float*)d_in[17]; const float* ln1b = (const float*)d_in[18];
    const float* ln2a = (const float*)d_in[19]; const float* ln2b = (const float*)d_in[20];
    const float* lnfa = (const float*)d_in[21]; const float* lnfb = (const float*)d_in[22];

    const size_t rows = (size_t)kB * kN;          // 8192
    const size_t actN = rows * kD;                // 2,097,152 elems

    char* wsb = (char*)d_ws;
    bf16*  pcb   = (bf16*)wsb;  wsb += (size_t)kB * kN * kN * sizeof(bf16);
    float* xc    = (float*)wsb; wsb += actN * sizeof(float);
    bf16*  h     = (bf16*)wsb;  wsb += actN * sizeof(bf16);
    bf16*  h2    = (bf16*)wsb;  wsb += actN * sizeof(bf16);
    bf16*  attb  = (bf16*)wsb;  wsb += actN * sizeof(bf16);
    bf16*  qkvb  = (bf16*)wsb;  wsb += 3 * actN * sizeof(bf16);
    bf16*  wqkv  = (bf16*)wsb;  wsb += (size_t)kL * 768 * kD * sizeof(bf16);
    bf16*  wo_t  = (bf16*)wsb;  wsb += (size_t)kL * kD * kD * sizeof(bf16);
    bf16*  wf1_t = (bf16*)wsb;  wsb += (size_t)kL * kD * kD * sizeof(bf16);
    bf16*  wf2_t = (bf16*)wsb;  wsb += (size_t)kL * kD * kD * sizeof(bf16);
    float* bcat  = (float*)wsb; wsb += (size_t)kL * 768 * sizeof(float);
    unsigned* mpk = (unsigned*)wsb; wsb += 256 * sizeof(unsigned);

    ln_init<<<rows, 256, 0, stream>>>(x, ln1a, ln1b, xc, h);
    wconv_kernel<<<24 * 64, 256, 0, stream>>>(Wq, Wk, Wv, Wo, Wf1, Wf2, wqkv, wo_t, wf1_t, wf2_t);
    bcat_kernel<<<kL * 768 / 256, 256, 0, stream>>>(bq, bk, bv, bcat);
    mpack_kernel<<<1, 256, 0, stream>>>(mask, mpk);
    pc_kernel<<<kB * kN, 256, 0, stream>>>(adj, dist, mask, pcb);

    dim3 gQKV(64, 12);    // (8192/128) x (768/64), MT=2
    dim3 gF1(128, 4);     // (8192/64)  x (256/64), MT=1
    dim3 gPCV(8, 2, kB);  // (512/64) x (256/128) x B
    for (int i = 0; i < kL; i++) {
        const size_t bOff = (size_t)i * kD;
        gemm_mfma<EPI_QKV, 2><<<gQKV, 256, 0, stream>>>(h, wqkv + (size_t)i * 768 * kD,
                                                        bcat + (size_t)i * 768, qkvb);
        pcv_gemm<<<gPCV, 256, 0, stream>>>(pcb, qkvb + 2 * actN, attb);
        attn_mfma<<<kB * kH * (kN / 64), 256, 0, stream>>>(qkvb, qkvb + actN, qkvb + 2 * actN,
                                                           mpk, attb);
        // Wo + residual + fused LN2 -> xc, h
        gemm_nfull<0><<<rows / 64, 256, 0, stream>>>(attb, wo_t + (size_t)i * kD * kD,
                                                     bo + bOff, xc,
                                                     ln2a + bOff, ln2b + bOff,
                                                     xc, h, nullptr, 0);
        gemm_mfma<EPI_LRELU, 1><<<gF1, 256, 0, stream>>>(h, wf1_t + (size_t)i * kD * kD,
                                                         bf1 + bOff, h2);
        // F2 + residual + fused LN1(next) (or final LN on last layer -> d_out)
        int lastL = (i == kL - 1);
        gemm_nfull<1><<<rows / 64, 256, 0, stream>>>(h2, wf2_t + (size_t)i * kD * kD,
                                                     bf2 + bOff, xc,
                                                     lastL ? lnfa : ln1a + (size_t)(i + 1) * kD,
                                                     lastL ? lnfb : ln1b + (size_t)(i + 1) * kD,
                                                     xc, h, (float*)d_out, lastL);
    }
}